// Round 6
// baseline (399.929 us; speedup 1.0000x reference)
//
#include <hip/hip_runtime.h>
#include <math.h>

// GPTBigCodeAttention: B=2,S=2048,D=2048,H=16,HD=128, MQA (1 shared K/V head)
constexpr int cB  = 2;
constexpr int cS  = 2048;
constexpr int cD  = 2048;
constexpr int cH  = 16;
constexpr int cHD = 128;
constexpr int cNQKV = cH * cHD + 2 * cHD;   // 2304

typedef __attribute__((ext_vector_type(8))) short bf16x8;
typedef __attribute__((ext_vector_type(4))) float f32x4;

__device__ __forceinline__ short f2bf(float f) {
    union { float f; unsigned u; } v; v.f = f;
    unsigned r = (v.u + 0x7FFFu + ((v.u >> 16) & 1u)) >> 16;
    return (short)r;
}

typedef __attribute__((address_space(3))) void lds_t;
typedef const __attribute__((address_space(1))) void gbl_t;
__device__ __forceinline__ void gld16(const void* g, void* l) {
    __builtin_amdgcn_global_load_lds((gbl_t*)g, (lds_t*)l, 16, 0, 0);
}

// ---------------------------------------------------------------------------
// elementwise fp32 -> bf16 (8 elems/thread)
// ---------------------------------------------------------------------------
__global__ __launch_bounds__(256) void conv_bf16(
    const float* __restrict__ src, short* __restrict__ dst)
{
    size_t i = ((size_t)blockIdx.x * 256 + threadIdx.x) * 8;
    float4 a = *(const float4*)(src + i);
    float4 b = *(const float4*)(src + i + 4);
    bf16x8 o;
    o[0] = f2bf(a.x); o[1] = f2bf(a.y); o[2] = f2bf(a.z); o[3] = f2bf(a.w);
    o[4] = f2bf(b.x); o[5] = f2bf(b.y); o[6] = f2bf(b.z); o[7] = f2bf(b.w);
    *(bf16x8*)(dst + i) = o;
}

// ---------------------------------------------------------------------------
// W fp32 [K][N] -> bf16 [N][K] (transpose), 32x32 LDS tiles
// ---------------------------------------------------------------------------
__global__ __launch_bounds__(256) void transpose_bf16(
    const float* __restrict__ src, short* __restrict__ dst, int K, int N)
{
    __shared__ short t[32][33];
    const int n0 = blockIdx.x * 32, k0 = blockIdx.y * 32;
    const int x = threadIdx.x & 31, y = threadIdx.x >> 5;
#pragma unroll
    for (int i = 0; i < 4; ++i)
        t[y + 8 * i][x] = f2bf(src[(size_t)(k0 + y + 8 * i) * N + n0 + x]);
    __syncthreads();
#pragma unroll
    for (int i = 0; i < 4; ++i)
        dst[(size_t)(n0 + y + 8 * i) * K + k0 + x] = t[x][y + 8 * i];
}

// ---------------------------------------------------------------------------
// bf16 MFMA GEMM (m97 structure): C[M][N] = A[M][K] @ Bt[N][K]^T + bias
// ---------------------------------------------------------------------------
template<bool BF16_OUT>
__global__ __launch_bounds__(256) void gemm_mfma(
    const short* __restrict__ A, const short* __restrict__ Bt,
    const float* __restrict__ bias, void* __restrict__ Cout,
    int M, int N, int K, float qscale, int qcols)
{
    __shared__ short As[128 * 32];
    __shared__ short Bs[128 * 32];

    const int tid = threadIdx.x;
    const int lane = tid & 63, n16 = lane & 15, quad = lane >> 4;
    const int wave = tid >> 6, wm = wave >> 1, wn = wave & 1;
    const int m0 = blockIdx.y * 128, n0 = blockIdx.x * 128;

    f32x4 acc[4][4];
#pragma unroll
    for (int i = 0; i < 4; ++i)
#pragma unroll
        for (int j = 0; j < 4; ++j) acc[i][j] = 0.0f;

    const int s0 = tid, s1 = tid + 256;
    const short* Ag0 = A  + (size_t)(m0 + (s0 >> 2)) * K + (s0 & 3) * 8;
    const short* Ag1 = A  + (size_t)(m0 + (s1 >> 2)) * K + (s1 & 3) * 8;
    const short* Bg0 = Bt + (size_t)(n0 + (s0 >> 2)) * K + (s0 & 3) * 8;
    const short* Bg1 = Bt + (size_t)(n0 + (s1 >> 2)) * K + (s1 & 3) * 8;

    for (int k0 = 0; k0 < K; k0 += 32) {
        gld16(Ag0 + k0, &As[s0 * 8]);
        gld16(Ag1 + k0, &As[s1 * 8]);
        gld16(Bg0 + k0, &Bs[s0 * 8]);
        gld16(Bg1 + k0, &Bs[s1 * 8]);
        __syncthreads();
        bf16x8 af[4], bfr[4];
#pragma unroll
        for (int mt = 0; mt < 4; ++mt)
            af[mt] = *(const bf16x8*)&As[(wm * 64 + mt * 16 + n16) * 32 + quad * 8];
#pragma unroll
        for (int nt = 0; nt < 4; ++nt)
            bfr[nt] = *(const bf16x8*)&Bs[(wn * 64 + nt * 16 + n16) * 32 + quad * 8];
#pragma unroll
        for (int mt = 0; mt < 4; ++mt)
#pragma unroll
            for (int nt = 0; nt < 4; ++nt)
                acc[mt][nt] = __builtin_amdgcn_mfma_f32_16x16x32_bf16(
                    af[mt], bfr[nt], acc[mt][nt], 0, 0, 0);
        __syncthreads();
    }

#pragma unroll
    for (int nt = 0; nt < 4; ++nt) {
        const int col = n0 + wn * 64 + nt * 16 + n16;
        const float bv = bias[col];
        const float sc = (col < qcols) ? qscale : 1.0f;
#pragma unroll
        for (int mt = 0; mt < 4; ++mt)
#pragma unroll
            for (int r = 0; r < 4; ++r) {
                const int row = m0 + wm * 64 + mt * 16 + quad * 4 + r;
                const float v = (acc[mt][nt][r] + bv) * sc;
                if (BF16_OUT) ((short*)Cout)[(size_t)row * N + col] = f2bf(v);
                else          ((float*)Cout)[(size_t)row * N + col] = v;
            }
    }
}

// ---------------------------------------------------------------------------
// V -> Vt bf16 [b][HD][S] transpose
// ---------------------------------------------------------------------------
__global__ __launch_bounds__(256) void prep_v(
    const short* __restrict__ qkvb, short* __restrict__ Vt)
{
    const int b  = blockIdx.y;
    const int k0 = blockIdx.x * 64;
    const int t  = threadIdx.x;
#pragma unroll
    for (int i = 0; i < 32; ++i) {
        int idx = i * 256 + t;
        int hd = idx >> 6, key = idx & 63;
        Vt[((size_t)b * cHD + hd) * cS + k0 + key] =
            qkvb[((size_t)(b * cS + k0 + key)) * cNQKV + cH * cHD + cHD + hd];
    }
}

// ---------------------------------------------------------------------------
// MFMA flash attention, k-split across waves. grid (S/64, H, B), 4 waves.
// Block = 64 q-rows x 1 head. Wave w processes 32-key tiles t = w, w+4, ...
// into wave-PRIVATE LDS (global_load_lds + manual vmcnt, NO barriers in the
// k-loop). Fixed-shift softmax => cross-wave merge is a pure SUM of O/l
// partials (4 quarter-passes through LDS at the end).
// XOR chunk-swizzle on K/V staging kills the 8-way frag-read bank conflicts.
// LDS carve (64 KB total): wave region w = lds16[w*8192 .. +8192):
//   K tile  [0,4096) shorts  (aliased by P matrix after QK, and O-frags at merge)
//   V tile  [4096,8192)      (wave 0's V half holds the l-sums at merge)
// ---------------------------------------------------------------------------
__global__ __launch_bounds__(256) void attn_mfma(
    const short* __restrict__ qkvb, const short* __restrict__ Vt,
    short* __restrict__ out)
{
    __shared__ short lds16[32768];   // 64 KB exactly

    const int tid  = threadIdx.x;
    const int wave = tid >> 6;
    const int lane = tid & 63;
    const int n16  = lane & 15;
    const int quad = lane >> 4;
    const int qt = (int)gridDim.x - 1 - (int)blockIdx.x;  // longest first
    const int h  = blockIdx.y;
    const int b  = blockIdx.z;
    const int q0b = qt * 64;                 // block q base (all 64 rows per wave)

    short* Kbuf = &lds16[wave * 8192];
    short* Vbuf = &lds16[wave * 8192 + 4096];
    short* Ps   = Kbuf;                      // alias: K dead once kf consumed

    // Q A-frags for 64 rows: qf[mt][ch], row = q0b + mt*16 + n16, k = ch*32+quad*8
    bf16x8 qf[4][4];
    {
        const short* qb = qkvb + ((size_t)(b * cS) + q0b + n16) * cNQKV + h * cHD + quad * 8;
#pragma unroll
        for (int mt = 0; mt < 4; ++mt)
#pragma unroll
            for (int ch = 0; ch < 4; ++ch)
                qf[mt][ch] = *(const bf16x8*)(qb + (size_t)(mt * 16) * cNQKV + ch * 32);
    }

    f32x4 oc[4][8];
#pragma unroll
    for (int mt = 0; mt < 4; ++mt)
#pragma unroll
        for (int on = 0; on < 8; ++on) oc[mt][on] = 0.0f;
    float lp[4][4] = {};

    const short* kglob = qkvb + (size_t)b * cS * cNQKV + cH * cHD;
    const short* vbase = Vt + (size_t)b * cHD * cS;
    const int nkt = 2 * (qt + 1);            // 32-key tiles

    // staging decode (loop-invariant parts)
    const int kkey_lo = lane >> 4;           // K: key = j*4 + this
    const int ksw     = lane & 15;
    const int vhd_lo  = lane >> 2;           // V: hd = j*16 + this
    const int vsw     = lane & 3;

    for (int t = wave; t < nkt; t += 4) {
        const int k0 = t * 32;

        // ---- stage K (8 KB) + V (8 KB), wave-private, swizzled sources ----
#pragma unroll
        for (int j = 0; j < 8; ++j) {
            const int key = j * 4 + kkey_lo;
            const int c16 = ksw ^ (key & 15);
            gld16(kglob + (size_t)(k0 + key) * cNQKV + c16 * 8, &Kbuf[j * 512 + lane * 8]);
        }
#pragma unroll
        for (int j = 0; j < 8; ++j) {
            const int hd = j * 16 + vhd_lo;
            const int kc = vsw ^ ((hd >> 2) & 3);
            gld16(vbase + (size_t)hd * cS + k0 + kc * 8, &Vbuf[j * 512 + lane * 8]);
        }
        __asm volatile("s_waitcnt vmcnt(0)" ::: "memory");

        // ---- S = Q @ K^T : sc[mt][nt] ----
        f32x4 sc[4][2];
#pragma unroll
        for (int mt = 0; mt < 4; ++mt) { sc[mt][0] = 0.0f; sc[mt][1] = 0.0f; }
#pragma unroll
        for (int nt = 0; nt < 2; ++nt) {
            const int key = nt * 16 + n16;
#pragma unroll
            for (int ch = 0; ch < 4; ++ch) {
                bf16x8 kf = *(const bf16x8*)&Kbuf[(key * 16 + (((ch * 4 + quad)) ^ n16)) * 8];
#pragma unroll
                for (int mt = 0; mt < 4; ++mt)
                    sc[mt][nt] = __builtin_amdgcn_mfma_f32_16x16x32_bf16(
                        qf[mt][ch], kf, sc[mt][nt], 0, 0, 0);
            }
        }

        // ---- causal mask (only tiles straddling the diagonal) ----
        if (k0 + 31 > q0b) {
#pragma unroll
            for (int mt = 0; mt < 4; ++mt)
#pragma unroll
                for (int nt = 0; nt < 2; ++nt)
#pragma unroll
                    for (int r = 0; r < 4; ++r) {
                        int row = q0b + mt * 16 + quad * 4 + r;
                        int col = k0 + nt * 16 + n16;
                        if (col > row) sc[mt][nt][r] = -1e30f;
                    }
        }

        // ---- p = exp(s); accumulate l; P -> LDS (stride 40 shorts) ----
#pragma unroll
        for (int mt = 0; mt < 4; ++mt)
#pragma unroll
            for (int r = 0; r < 4; ++r)
#pragma unroll
                for (int nt = 0; nt < 2; ++nt) {
                    float p = __expf(sc[mt][nt][r]);   // masked: exp(-1e30)=0
                    lp[mt][r] += p;
                    Ps[(mt * 16 + quad * 4 + r) * 40 + nt * 16 + n16] = f2bf(p);
                }

        // ---- P A-frags (K=32: one bf16x8 per m-tile) ----
        bf16x8 pf[4];
#pragma unroll
        for (int mt = 0; mt < 4; ++mt)
            pf[mt] = *(const bf16x8*)&Ps[(mt * 16 + n16) * 40 + quad * 8];

        // ---- O += P @ V ----
#pragma unroll
        for (int on = 0; on < 8; ++on) {
            const int hd = on * 16 + n16;
            bf16x8 vf = *(const bf16x8*)&Vbuf[(hd * 4 + (quad ^ (n16 >> 2))) * 8];
#pragma unroll
            for (int mt = 0; mt < 4; ++mt)
                oc[mt][on] = __builtin_amdgcn_mfma_f32_16x16x32_bf16(
                    pf[mt], vf, oc[mt][on], 0, 0, 0);
        }
    }

    // ================= cross-wave merge (additive: fixed-shift) =============
    __syncthreads();   // all waves done with their K/V regions

    // l partials: reduce over the 16 col-lanes, store to wave0's V half
    float* Lf = (float*)&lds16[4096];        // [wv][64 rows]
    {
#pragma unroll
        for (int mt = 0; mt < 4; ++mt)
#pragma unroll
            for (int r = 0; r < 4; ++r) {
                float s = lp[mt][r];
                s += __shfl_xor(s, 1);
                s += __shfl_xor(s, 2);
                s += __shfl_xor(s, 4);
                s += __shfl_xor(s, 8);
                lp[mt][r] = s;
            }
        if (n16 == 0) {
#pragma unroll
            for (int mt = 0; mt < 4; ++mt)
#pragma unroll
                for (int r = 0; r < 4; ++r)
                    Lf[wave * 64 + mt * 16 + quad * 4 + r] = lp[mt][r];
        }
    }

    float inv[4];
    short* obase = out + ((size_t)(b * cS) + q0b + wave * 16) * cD + h * cHD;

#pragma unroll
    for (int pass = 0; pass < 4; ++pass) {
        __syncthreads();  // pass 0: Lf visible; later: previous reads done
        // write my O quarter-frags (on = 2*pass, 2*pass+1) into my K half
#pragma unroll
        for (int mt = 0; mt < 4; ++mt)
#pragma unroll
            for (int oi = 0; oi < 2; ++oi)
                *(f32x4*)&lds16[wave * 8192 + (mt * 2 + oi) * 512 + lane * 8] =
                    oc[mt][2 * pass + oi];
        __syncthreads();
        if (pass == 0) {
#pragma unroll
            for (int r = 0; r < 4; ++r) {
                float lt = 0.0f;
#pragma unroll
                for (int wv = 0; wv < 4; ++wv)
                    lt += Lf[wv * 64 + wave * 16 + quad * 4 + r];
                inv[r] = 1.0f / lt;
            }
        }
        // sum the 4 wave-partials for my 16 rows (mt == wave), write global
#pragma unroll
        for (int oi = 0; oi < 2; ++oi) {
            f32x4 s = 0.0f;
#pragma unroll
            for (int wv = 0; wv < 4; ++wv)
                s += *(const f32x4*)&lds16[wv * 8192 + (wave * 2 + oi) * 512 + lane * 8];
            const int col = (2 * pass + oi) * 16 + n16;
#pragma unroll
            for (int r = 0; r < 4; ++r)
                obase[(size_t)(quad * 4 + r) * cD + col] = f2bf(s[r] * inv[r]);
        }
    }
}

// ---------------------------------------------------------------------------
extern "C" void kernel_launch(void* const* d_in, const int* in_sizes, int n_in,
                              void* d_out, int out_size, void* d_ws, size_t ws_size,
                              hipStream_t stream)
{
    const float* hidden = (const float*)d_in[0];
    const float* W_attn = (const float*)d_in[1];
    const float* b_attn = (const float*)d_in[2];
    const float* W_proj = (const float*)d_in[3];
    const float* b_proj = (const float*)d_in[4];
    float* out = (float*)d_out;

    const int M = cB * cS;  // 4096
    short* qkvb = (short*)d_ws;
    short* Ah   = qkvb + (size_t)M * cNQKV;
    short* Wb   = Ah   + (size_t)M * cD;
    short* Wpb  = Wb   + (size_t)cNQKV * cD;
    short* Vt   = Wpb  + (size_t)cD * cD;
    short* attno = Ah;  // alias: Ah dead after GEMM1

    const float scale = 0.088388347648318447f;  // 1/sqrt(128)

    conv_bf16<<<(size_t)M * cD / 2048, 256, 0, stream>>>(hidden, Ah);
    transpose_bf16<<<dim3(cNQKV / 32, cD / 32), 256, 0, stream>>>(W_attn, Wb, cD, cNQKV);
    transpose_bf16<<<dim3(cD / 32, cD / 32), 256, 0, stream>>>(W_proj, Wpb, cD, cD);

    gemm_mfma<true><<<dim3(cNQKV / 128, M / 128), 256, 0, stream>>>(
        Ah, Wb, b_attn, qkvb, M, cNQKV, cD, scale, cH * cHD);

    prep_v<<<dim3(cS / 64, cB), 256, 0, stream>>>(qkvb, Vt);

    attn_mfma<<<dim3(cS / 64, cH, cB), 256, 0, stream>>>(qkvb, Vt, attno);

    gemm_mfma<false><<<dim3(cD / 128, M / 128), 256, 0, stream>>>(
        attno, Wpb, b_proj, out, M, cD, cD, 1.0f, 0);
}